// Round 4
// baseline (408.339 us; speedup 1.0000x reference)
//
#include <hip/hip_runtime.h>
#include <math.h>

// Problem dims (fixed by reference)
#define BB 32
#define DD 256
#define TT 1024
#define KK 1024
#define NN (BB*TT)          // 32768 rows

// argmin-GEMM tiling
#define BROWS 64            // rows per block
#define CCH   256           // codes per chunk
#define DSL   32            // d per slice (halved -> fits double-buffered pipeline in 80 KB)
#define NSTEP 32            // 4 chunks x 8 slices

// ---------------------------------------------------------------------------
// ws layout (elements): float wsq[1024] @0 ; int counts[1024] @1024 ; float sse @2048
// ---------------------------------------------------------------------------

// wsq[k] = sum_d W[k,d]^2 (fp64 accumulate, round once). Zeroes counts+sse.
__global__ void prep_kernel(const float* __restrict__ W, float* __restrict__ wsq,
                            int* __restrict__ counts, float* __restrict__ sse) {
    const int k = blockIdx.x;          // 1024 blocks, 64 threads
    const int lane = threadIdx.x;
    const float4 v = ((const float4*)(W + (size_t)k * DD))[lane];
    double s = (double)v.x * v.x + (double)v.y * v.y + (double)v.z * v.z + (double)v.w * v.w;
    #pragma unroll
    for (int m = 32; m > 0; m >>= 1) s += __shfl_down(s, m);
    if (lane == 0) wsq[k] = (float)s;
    if (blockIdx.x < 16) counts[blockIdx.x * 64 + lane] = 0;
    if (blockIdx.x == 0 && lane == 0) *sse = 0.0f;
}

// 8-slot (DSL=32 -> 8 float4 groups/row) swizzles.
// W: slot = q ^ ((r>>3)&7)  -> reads 2-way (free), gl_lds dest linear + pre-swizzled source.
__device__ __forceinline__ int swz_w(int r, int q) { return r * 8 + (q ^ ((r >> 3) & 7)); }
// z: extra ^(r&7) -> staging ds_writes 2-way/phase (free); reads are broadcast.
__device__ __forceinline__ int swz_z(int r, int q) { return r * 8 + (q ^ (r & 7) ^ ((r >> 3) & 7)); }

// async global->LDS, 16B/lane; LDS dest = wave-uniform base + lane*16 (linear).
__device__ __forceinline__ void gl_lds16(const float* g, void* l) {
    __builtin_amdgcn_global_load_lds((const __attribute__((address_space(1))) void*)g,
                                     (__attribute__((address_space(3))) void*)l, 16, 0, 0);
}

// Fused: rowsq + argmin-GEMM (2-phase pipelined staging) + gather/ST/SSE/counts.
// Block: 64 rows x all 1024 codes (4 chunks of 256). 256 thr = 8(ty) x 32(tx), 8x8 tile.
// dist mirrors np:  s1 = fl(rowsq + wsq);  v = fmaf(-2, dot, s1).
// Per-(row,code) dot: single sequential fmaf chain over d=0..255 in order
// (slices asc, q asc, x/y/z/w) — bitwise-matches BLAS k-order; validated absmax==0.0
// three times. DO NOT reorder.
__global__ __launch_bounds__(256, 2) void vq_fused_kernel(
    const float* __restrict__ z, const float* __restrict__ W,
    const float* __restrict__ wsq, float* __restrict__ out,
    int* __restrict__ counts, float* __restrict__ sse)
{
    __shared__ float4 zs[2][BROWS * 8];   // 2 x 8 KB  (zs[0] reused as scratch at the end)
    __shared__ float4 ws[2][CCH * 8];     // 2 x 32 KB
    const int tid = threadIdx.x;
    const int tx = tid & 31, ty = tid >> 5;
    const int w = tid >> 6, lane = tid & 63;
    const int row0 = blockIdx.x * BROWS;
    const int b = row0 >> 10, t0 = row0 & 1023;
    const size_t bbase = (size_t)b * DD * TT;
    const float* zbase = z + bbase + t0;

    // ---- phase 0: per-wave rowsq (fp64, bitwise == ((g0+g1)+(g2+g3)) of 64-elem chains)
    float rsq[8];
    {
        const int ro = lane & 15;          // row offset within wave's 16 rows
        const int g  = lane >> 4;          // d-quarter 0..3
        const float* zp = zbase + (size_t)g * 64 * TT + (16 * w + ro);
        double s = 0.0;
        #pragma unroll 4
        for (int d = 0; d < 64; ++d) { float v = zp[(size_t)d * TT]; s += (double)v * v; }
        s += __shfl_xor(s, 16);            // g0+g1 / g2+g3 (fp64 add commutative: bitwise safe)
        s += __shfl_xor(s, 32);            // (g0+g1)+(g2+g3)
        float f = (float)s;
        #pragma unroll
        for (int i = 0; i < 8; ++i) rsq[i] = __shfl(f, (ty & 1) * 8 + i);
    }

    float minv[8]; int mini[8];
    #pragma unroll
    for (int i = 0; i < 8; ++i) { minv[i] = 3.4e38f; mini[i] = 0; }

    // staging identities
    const int zr  = lane;            // z row 0..63 (coalesced over t)
    const int zq0 = w * 2;           // z q-groups: 2 per thread
    const int wlr = lane >> 3;       // W lane row-in-8
    const int wls = lane & 7;        // W lane slot
    float4 zreg[2];

    // stage W tile for step t into ws[t&1]: ch=t>>3, sl=t&7 (linear dest, pre-swz src)
    auto STAGE_W = [&](int t) {
        const int ch = t >> 3, sl = t & 7;
        const float* wch = W + (size_t)(ch * CCH) * DD + sl * DSL;
        char* dst = (char*)&ws[t & 1][0] + (size_t)w * 8192;
        #pragma unroll
        for (int k = 0; k < 8; ++k) {
            const int r = w * 64 + k * 8 + wlr;
            const float* g = wch + (size_t)r * DD + 4 * (wls ^ k);
            gl_lds16(g, dst + k * 1024);
        }
    };
    // load z slab regs for step t (sl = t&7): 8 scalar coalesced loads
    auto LOAD_Z = [&](int t) {
        const int sl = t & 7;
        #pragma unroll
        for (int j = 0; j < 2; ++j) {
            const float* zp = zbase + (size_t)(sl * DSL + (zq0 + j) * 4) * TT + zr;
            zreg[j].x = zp[0]; zreg[j].y = zp[(size_t)TT];
            zreg[j].z = zp[(size_t)2 * TT]; zreg[j].w = zp[(size_t)3 * TT];
        }
    };
    // write z slab for step t into zs[t&1]
    auto WRITE_Z = [&](int t) {
        #pragma unroll
        for (int j = 0; j < 2; ++j) zs[t & 1][swz_z(zr, zq0 + j)] = zreg[j];
    };

    // prologue: fill buffers for step 0, preload z regs for step 1
    LOAD_Z(0);
    STAGE_W(0);
    WRITE_Z(0);          // compiler waits zreg's vmcnt (not the gl_lds just issued)
    LOAD_Z(1);

    float acc[8][8];
    float wq[8];

    for (int s = 0; s < NSTEP; ++s) {
        const int sl = s & 7, ch = s >> 3;
        __syncthreads();   // drains this wave's gl_lds/ds_writes; buffers [s&1] ready
        // issue next step's staging NOW; it lands during compute (no exposed latency)
        if (s + 1 < NSTEP) {
            STAGE_W(s + 1);
            WRITE_Z(s + 1);
            if (s + 2 < NSTEP) LOAD_Z(s + 2);
        }
        if (sl == 0) {
            #pragma unroll
            for (int i = 0; i < 8; ++i)
                #pragma unroll
                for (int j = 0; j < 8; ++j) acc[i][j] = 0.0f;
            #pragma unroll
            for (int j = 0; j < 8; ++j) wq[j] = wsq[ch * CCH + tx * 8 + j];
        }
        // 8x8x(32d) register-tile FMA; d-order: q ascending, then x,y,z,w
        #pragma unroll
        for (int q = 0; q < 8; ++q) {
            float4 zf[8], wf[8];
            #pragma unroll
            for (int i = 0; i < 8; ++i) zf[i] = zs[s & 1][swz_z(ty * 8 + i, q)];
            #pragma unroll
            for (int j = 0; j < 8; ++j) wf[j] = ws[s & 1][swz_w(tx * 8 + j, q)];
            #pragma unroll
            for (int i = 0; i < 8; ++i)
                #pragma unroll
                for (int j = 0; j < 8; ++j) {
                    acc[i][j] = fmaf(zf[i].x, wf[j].x, acc[i][j]);
                    acc[i][j] = fmaf(zf[i].y, wf[j].y, acc[i][j]);
                    acc[i][j] = fmaf(zf[i].z, wf[j].z, acc[i][j]);
                    acc[i][j] = fmaf(zf[i].w, wf[j].w, acc[i][j]);
                }
        }
        if (sl == 7) {
            // score + running argmin (codes ascending -> first-min like np.argmin)
            #pragma unroll
            for (int j = 0; j < 8; ++j) {
                int c = ch * CCH + tx * 8 + j;
                #pragma unroll
                for (int i = 0; i < 8; ++i) {
                    float s1 = rsq[i] + wq[j];               // rounding 1 (np A+B)
                    float v = fmaf(-2.0f, acc[i][j], s1);    // rounding 2 (np (A+B)-2P)
                    if (v < minv[i]) { minv[i] = v; mini[i] = c; }
                }
            }
        }
    }

    __syncthreads();                 // all compute done; zs[0] becomes scratch
    int* idxs = (int*)&zs[0][0];     // 64 ints
    float* ssescr = (float*)&zs[0][0] + 64;
    // reduce across the 32 tx lanes of each row; ties -> lowest index
    #pragma unroll
    for (int i = 0; i < 8; ++i) {
        float v = minv[i]; int ix = mini[i];
        #pragma unroll
        for (int m = 1; m < 32; m <<= 1) {
            float ov = __shfl_xor(v, m);
            int   oi = __shfl_xor(ix, m);
            if (ov < v || (ov == v && oi < ix)) { v = ov; ix = oi; }
        }
        if (tx == 0) {
            idxs[ty * 8 + i] = ix;
            atomicAdd(&counts[ix], 1);
        }
    }
    __syncthreads();

    // ---- fused gather / straight-through / SSE over this block's 64 rows x 256 d
    const int tg = tid & 15;       // t-quarter (4 rows)
    const int dg = tid >> 4;       // 16 d-groups of 16
    const int t4 = tg * 4;
    int ixs[4];
    #pragma unroll
    for (int m = 0; m < 4; ++m) ixs[m] = idxs[t4 + m];
    float ssel = 0.0f;
    #pragma unroll
    for (int k4 = 0; k4 < 4; ++k4) {
        const int d0 = dg * 16 + k4 * 4;
        float wr[4][4];
        #pragma unroll
        for (int m = 0; m < 4; ++m) {
            float4 wv = *(const float4*)(W + (size_t)ixs[m] * DD + d0);
            wr[m][0] = wv.x; wr[m][1] = wv.y; wr[m][2] = wv.z; wr[m][3] = wv.w;
        }
        #pragma unroll
        for (int dd = 0; dd < 4; ++dd) {
            const int d = d0 + dd;
            const size_t base = bbase + (size_t)d * TT + t0 + t4;
            float4 zv = *(const float4*)(z + base);
            float e0 = wr[0][dd] - zv.x, e1 = wr[1][dd] - zv.y;
            float e2 = wr[2][dd] - zv.z, e3 = wr[3][dd] - zv.w;
            float4 o;
            o.x = zv.x + e0; o.y = zv.y + e1; o.z = zv.z + e2; o.w = zv.w + e3;
            *(float4*)(out + base) = o;
            ssel += (e0 * e0 + e1 * e1) + (e2 * e2 + e3 * e3);
        }
    }
    #pragma unroll
    for (int m = 32; m > 0; m >>= 1) ssel += __shfl_down(ssel, m);
    if (lane == 0) ssescr[w] = ssel;
    __syncthreads();
    if (tid == 0) atomicAdd(sse, (ssescr[0] + ssescr[1]) + (ssescr[2] + ssescr[3]));
}

// reg_loss = 1.25 * sse / numel ; perplexity = exp(-sum p*log(p+1e-10))
__global__ void finalize_kernel(const int* __restrict__ counts, const float* __restrict__ sse,
                                float* __restrict__ out) {
    float s = 0.0f;
    for (int k = threadIdx.x; k < KK; k += 256) {
        float p = (float)counts[k] / (float)NN;
        s += p * logf(p + 1e-10f);
    }
    #pragma unroll
    for (int m = 32; m > 0; m >>= 1) s += __shfl_down(s, m);
    __shared__ float wsum[4];
    if ((threadIdx.x & 63) == 0) wsum[threadIdx.x >> 6] = s;
    __syncthreads();
    if (threadIdx.x == 0) {
        float ent = (wsum[0] + wsum[1]) + (wsum[2] + wsum[3]);
        out[(size_t)BB * DD * TT]     = 1.25f * (*sse) / (float)(BB * DD * TT);
        out[(size_t)BB * DD * TT + 1] = expf(-ent);
    }
}

extern "C" void kernel_launch(void* const* d_in, const int* in_sizes, int n_in,
                              void* d_out, int out_size, void* d_ws, size_t ws_size,
                              hipStream_t stream) {
    const float* z = (const float*)d_in[0];   // (32, 256, 1024) fp32
    const float* W = (const float*)d_in[1];   // (1024, 256) fp32
    float* out = (float*)d_out;               // 8388608 + 2 fp32

    float* wsq    = (float*)d_ws;
    int*   counts = (int*)(wsq + 1024);
    float* sse    = (float*)(counts + 1024);

    prep_kernel<<<1024, 64, 0, stream>>>(W, wsq, counts, sse);
    vq_fused_kernel<<<NN / BROWS, 256, 0, stream>>>(z, W, wsq, out, counts, sse);
    finalize_kernel<<<1, 256, 0, stream>>>(counts, sse, out);
}

// Round 5
// 278.646 us; speedup vs baseline: 1.4654x; 1.4654x over previous
//
#include <hip/hip_runtime.h>
#include <math.h>

// Problem dims (fixed by reference)
#define BB 32
#define DD 256
#define TT 1024
#define KK 1024
#define NN (BB*TT)          // 32768 rows

// argmin-GEMM tiling
#define BROWS 64            // rows per block
#define CCH   256           // codes per chunk
#define WSL   32            // W d-slice per step (double-buffered)
#define NSTEP 32            // 4 chunks x 8 W-slices

// ---------------------------------------------------------------------------
// ws layout (elements): float wsq[1024] @0 ; int counts[1024] @1024 ; float sse @2048
// ---------------------------------------------------------------------------

// wsq[k] = sum_d W[k,d]^2 (fp64 accumulate, round once). Zeroes counts+sse.
__global__ void prep_kernel(const float* __restrict__ W, float* __restrict__ wsq,
                            int* __restrict__ counts, float* __restrict__ sse) {
    const int k = blockIdx.x;          // 1024 blocks, 64 threads
    const int lane = threadIdx.x;
    const float4 v = ((const float4*)(W + (size_t)k * DD))[lane];
    double s = (double)v.x * v.x + (double)v.y * v.y + (double)v.z * v.z + (double)v.w * v.w;
    #pragma unroll
    for (int m = 32; m > 0; m >>= 1) s += __shfl_down(s, m);
    if (lane == 0) wsq[k] = (float)s;
    if (blockIdx.x < 16) counts[blockIdx.x * 64 + lane] = 0;
    if (blockIdx.x == 0 && lane == 0) *sse = 0.0f;
}

// z slab: 16 float4 slots/row (64 d). Writes 2-way/phase (free); reads broadcast.
__device__ __forceinline__ int swz_z(int r, int q) { return r * 16 + (q ^ (r & 7) ^ ((r >> 3) & 7)); }
// W slice: 8 float4 slots/row (32 d). slot = q ^ ((r>>3)&7); gl_lds dest linear,
// source pre-swizzled (rule: swizzle both sides or neither).
__device__ __forceinline__ int swz_w(int r, int q) { return r * 8 + (q ^ ((r >> 3) & 7)); }

// async global->LDS, 16B/lane; LDS dest = wave-uniform base + lane*16 (linear).
__device__ __forceinline__ void gl_lds16(const float* g, void* l) {
    __builtin_amdgcn_global_load_lds((const __attribute__((address_space(1))) void*)g,
                                     (__attribute__((address_space(3))) void*)l, 16, 0, 0);
}

// Fused: rowsq + argmin-GEMM (W double-buffered, barrier never drains fresh loads)
// + gather/ST/SSE/counts.
// Block: 64 rows x 1024 codes (4 chunks of 256). 256 thr = 8(ty) x 32(tx), 8x8 tile.
// dist mirrors np:  s1 = fl(rowsq + wsq);  v = fmaf(-2, dot, s1).
// Per-(row,code) dot: single sequential fmaf chain over d=0..255 in order
// (steps asc, q asc, x/y/z/w) — bitwise-matches BLAS k-order; validated absmax==0.0.
// DO NOT reorder. DO NOT add #pragma unroll to the q-loop (R4 spill lesson).
__global__ __launch_bounds__(256, 2) void vq_fused_kernel(
    const float* __restrict__ z, const float* __restrict__ W,
    const float* __restrict__ wsq, float* __restrict__ out,
    int* __restrict__ counts, float* __restrict__ sse)
{
    __shared__ float4 zs[BROWS * 16];   // 16 KB single buffer (reused as scratch at end)
    __shared__ float4 ws[2][CCH * 8];   // 2 x 32 KB double buffer
    const int tid = threadIdx.x;
    const int tx = tid & 31, ty = tid >> 5;
    const int w = tid >> 6, lane = tid & 63;
    const int row0 = blockIdx.x * BROWS;
    const int b = row0 >> 10, t0 = row0 & 1023;
    const size_t bbase = (size_t)b * DD * TT;
    const float* zbase = z + bbase + t0;

    // staging identities
    const int zr  = lane;            // z row 0..63 (coalesced over t)
    const int zq0 = w * 4;           // z q-groups: 4 per thread (of 16)
    const int wlr = lane >> 3;       // W lane row-in-8
    const int wls = lane & 7;        // W lane slot
    float4 zreg[4];

    // ---- prologue staging: W slice for step 0, z slab 0 (latency hides under rowsq)
    {
        const float* wch = W;        // ch=0, sl=0
        char* dst = (char*)&ws[0][0] + (size_t)w * 8192;
        #pragma unroll
        for (int k = 0; k < 8; ++k) {
            const int r = w * 64 + k * 8 + wlr;
            gl_lds16(wch + (size_t)r * DD + 4 * (wls ^ k), dst + k * 1024);
        }
        #pragma unroll
        for (int j = 0; j < 4; ++j) {
            const float* zp = zbase + (size_t)((zq0 + j) * 4) * TT + zr;
            zreg[j].x = zp[0]; zreg[j].y = zp[(size_t)TT];
            zreg[j].z = zp[(size_t)2 * TT]; zreg[j].w = zp[(size_t)3 * TT];
        }
    }

    // ---- rowsq (fp64, bitwise == ((g0+g1)+(g2+g3)) of 64-elem sequential chains)
    float rsq[8];
    {
        const int ro = lane & 15;          // row offset within wave's 16 rows
        const int g  = lane >> 4;          // d-quarter 0..3
        const float* zp = zbase + (size_t)g * 64 * TT + (16 * w + ro);
        double s = 0.0;
        #pragma unroll 4
        for (int d = 0; d < 64; ++d) { float v = zp[(size_t)d * TT]; s += (double)v * v; }
        s += __shfl_xor(s, 16);            // fp64 add commutative: bitwise safe
        s += __shfl_xor(s, 32);
        float f = (float)s;
        #pragma unroll
        for (int i = 0; i < 8; ++i) rsq[i] = __shfl(f, (ty & 1) * 8 + i);
    }

    float minv[8]; int mini[8];
    #pragma unroll
    for (int i = 0; i < 8; ++i) { minv[i] = 3.4e38f; mini[i] = 0; }

    float acc[8][8];
    float wq[8];

    for (int s = 0; s < NSTEP; ++s) {
        const int h = s & 1, sl = s & 7, ch = s >> 3;
        __syncthreads();   // sync_A: prev compute done; ws[s&1] gl_lds landed (issued
                           // a full compute phase ago -> drain ~free)
        if (h == 0) {
            // write z slab (steps s, s+1) from regs; 2-way/phase swizzle
            #pragma unroll
            for (int j = 0; j < 4; ++j) zs[swz_z(zr, zq0 + j)] = zreg[j];
            __syncthreads();   // sync_B: only local ds_writes outstanding -> cheap
        }
        // issue next step's W staging NOW; lands during compute below
        if (s + 1 < NSTEP) {
            const int t = s + 1, sln = t & 7, chn = t >> 3;
            const float* wch = W + (size_t)(chn * CCH) * DD + sln * WSL;
            char* dst = (char*)&ws[t & 1][0] + (size_t)w * 8192;
            #pragma unroll
            for (int k = 0; k < 8; ++k) {
                const int r = w * 64 + k * 8 + wlr;
                gl_lds16(wch + (size_t)r * DD + 4 * (wls ^ k), dst + k * 1024);
            }
        }
        // prefetch z slab for steps s+2, s+3 (even steps only)
        if (h == 0 && s + 2 < NSTEP) {
            const int mn = ((s + 2) & 7) >> 1;
            #pragma unroll
            for (int j = 0; j < 4; ++j) {
                const float* zp = zbase + (size_t)(mn * 64 + (zq0 + j) * 4) * TT + zr;
                zreg[j].x = zp[0]; zreg[j].y = zp[(size_t)TT];
                zreg[j].z = zp[(size_t)2 * TT]; zreg[j].w = zp[(size_t)3 * TT];
            }
        }
        if (sl == 0) {
            #pragma unroll
            for (int i = 0; i < 8; ++i)
                #pragma unroll
                for (int j = 0; j < 8; ++j) acc[i][j] = 0.0f;
            #pragma unroll
            for (int j = 0; j < 8; ++j) wq[j] = wsq[ch * CCH + tx * 8 + j];
        }
        // 8x8x(32d) register-tile FMA; d-order: q ascending, then x,y,z,w
        const int qb = 8 * h;
        for (int q = 0; q < 8; ++q) {       // no unroll pragma (R4 spill lesson)
            float4 zf[8], wf[8];
            #pragma unroll
            for (int i = 0; i < 8; ++i) zf[i] = zs[swz_z(ty * 8 + i, qb + q)];
            #pragma unroll
            for (int j = 0; j < 8; ++j) wf[j] = ws[h][swz_w(tx * 8 + j, q)];
            #pragma unroll
            for (int i = 0; i < 8; ++i)
                #pragma unroll
                for (int j = 0; j < 8; ++j) {
                    acc[i][j] = fmaf(zf[i].x, wf[j].x, acc[i][j]);
                    acc[i][j] = fmaf(zf[i].y, wf[j].y, acc[i][j]);
                    acc[i][j] = fmaf(zf[i].z, wf[j].z, acc[i][j]);
                    acc[i][j] = fmaf(zf[i].w, wf[j].w, acc[i][j]);
                }
        }
        if (sl == 7) {
            // score + running argmin (codes ascending -> first-min like np.argmin)
            #pragma unroll
            for (int j = 0; j < 8; ++j) {
                int c = ch * CCH + tx * 8 + j;
                #pragma unroll
                for (int i = 0; i < 8; ++i) {
                    float s1 = rsq[i] + wq[j];               // rounding 1 (np A+B)
                    float v = fmaf(-2.0f, acc[i][j], s1);    // rounding 2 (np (A+B)-2P)
                    if (v < minv[i]) { minv[i] = v; mini[i] = c; }
                }
            }
        }
    }

    __syncthreads();                 // all compute done; zs becomes scratch
    int* idxs = (int*)&zs[0];        // 64 ints
    float* ssescr = (float*)&zs[0] + 64;
    // reduce across the 32 tx lanes of each row; ties -> lowest index
    #pragma unroll
    for (int i = 0; i < 8; ++i) {
        float v = minv[i]; int ix = mini[i];
        #pragma unroll
        for (int m = 1; m < 32; m <<= 1) {
            float ov = __shfl_xor(v, m);
            int   oi = __shfl_xor(ix, m);
            if (ov < v || (ov == v && oi < ix)) { v = ov; ix = oi; }
        }
        if (tx == 0) {
            idxs[ty * 8 + i] = ix;
            atomicAdd(&counts[ix], 1);
        }
    }
    __syncthreads();

    // ---- fused gather / straight-through / SSE over this block's 64 rows x 256 d
    const int tg = tid & 15;       // t-quarter (4 rows)
    const int dg = tid >> 4;       // 16 d-groups of 16
    const int t4 = tg * 4;
    int ixs[4];
    #pragma unroll
    for (int m = 0; m < 4; ++m) ixs[m] = idxs[t4 + m];
    float ssel = 0.0f;
    #pragma unroll
    for (int k4 = 0; k4 < 4; ++k4) {
        const int d0 = dg * 16 + k4 * 4;
        float wr[4][4];
        #pragma unroll
        for (int m = 0; m < 4; ++m) {
            float4 wv = *(const float4*)(W + (size_t)ixs[m] * DD + d0);
            wr[m][0] = wv.x; wr[m][1] = wv.y; wr[m][2] = wv.z; wr[m][3] = wv.w;
        }
        #pragma unroll
        for (int dd = 0; dd < 4; ++dd) {
            const int d = d0 + dd;
            const size_t base = bbase + (size_t)d * TT + t0 + t4;
            float4 zv = *(const float4*)(z + base);
            float e0 = wr[0][dd] - zv.x, e1 = wr[1][dd] - zv.y;
            float e2 = wr[2][dd] - zv.z, e3 = wr[3][dd] - zv.w;
            float4 o;
            o.x = zv.x + e0; o.y = zv.y + e1; o.z = zv.z + e2; o.w = zv.w + e3;
            *(float4*)(out + base) = o;
            ssel += (e0 * e0 + e1 * e1) + (e2 * e2 + e3 * e3);
        }
    }
    #pragma unroll
    for (int m = 32; m > 0; m >>= 1) ssel += __shfl_down(ssel, m);
    if (lane == 0) ssescr[w] = ssel;
    __syncthreads();
    if (tid == 0) atomicAdd(sse, (ssescr[0] + ssescr[1]) + (ssescr[2] + ssescr[3]));
}

// reg_loss = 1.25 * sse / numel ; perplexity = exp(-sum p*log(p+1e-10))
__global__ void finalize_kernel(const int* __restrict__ counts, const float* __restrict__ sse,
                                float* __restrict__ out) {
    float s = 0.0f;
    for (int k = threadIdx.x; k < KK; k += 256) {
        float p = (float)counts[k] / (float)NN;
        s += p * logf(p + 1e-10f);
    }
    #pragma unroll
    for (int m = 32; m > 0; m >>= 1) s += __shfl_down(s, m);
    __shared__ float wsum[4];
    if ((threadIdx.x & 63) == 0) wsum[threadIdx.x >> 6] = s;
    __syncthreads();
    if (threadIdx.x == 0) {
        float ent = (wsum[0] + wsum[1]) + (wsum[2] + wsum[3]);
        out[(size_t)BB * DD * TT]     = 1.25f * (*sse) / (float)(BB * DD * TT);
        out[(size_t)BB * DD * TT + 1] = expf(-ent);
    }
}

extern "C" void kernel_launch(void* const* d_in, const int* in_sizes, int n_in,
                              void* d_out, int out_size, void* d_ws, size_t ws_size,
                              hipStream_t stream) {
    const float* z = (const float*)d_in[0];   // (32, 256, 1024) fp32
    const float* W = (const float*)d_in[1];   // (1024, 256) fp32
    float* out = (float*)d_out;               // 8388608 + 2 fp32

    float* wsq    = (float*)d_ws;
    int*   counts = (int*)(wsq + 1024);
    float* sse    = (float*)(counts + 1024);

    prep_kernel<<<1024, 64, 0, stream>>>(W, wsq, counts, sse);
    vq_fused_kernel<<<NN / BROWS, 256, 0, stream>>>(z, W, wsq, out, counts, sse);
    finalize_kernel<<<1, 256, 0, stream>>>(counts, sse, out);
}

// Round 6
// 277.628 us; speedup vs baseline: 1.4708x; 1.0037x over previous
//
#include <hip/hip_runtime.h>
#include <math.h>

// Problem dims (fixed by reference)
#define BB 32
#define DD 256
#define TT 1024
#define KK 1024
#define NN (BB*TT)          // 32768 rows

// argmin-GEMM tiling
#define BROWS 64            // rows per block
#define CCH   256           // codes per chunk
#define WSL   32            // W d-slice per step (double-buffered)
#define NSTEP 32            // 4 chunks x 8 W-slices

// ---------------------------------------------------------------------------
// ws layout (elements): float wsq[1024] @0 ; int counts[1024] @1024 ; float sse @2048
// ---------------------------------------------------------------------------

// wsq[k] = sum_d W[k,d]^2 (fp64 accumulate, round once). Zeroes counts+sse.
__global__ void prep_kernel(const float* __restrict__ W, float* __restrict__ wsq,
                            int* __restrict__ counts, float* __restrict__ sse) {
    const int k = blockIdx.x;          // 1024 blocks, 64 threads
    const int lane = threadIdx.x;
    const float4 v = ((const float4*)(W + (size_t)k * DD))[lane];
    double s = (double)v.x * v.x + (double)v.y * v.y + (double)v.z * v.z + (double)v.w * v.w;
    #pragma unroll
    for (int m = 32; m > 0; m >>= 1) s += __shfl_down(s, m);
    if (lane == 0) wsq[k] = (float)s;
    if (blockIdx.x < 16) counts[blockIdx.x * 64 + lane] = 0;
    if (blockIdx.x == 0 && lane == 0) *sse = 0.0f;
}

// W slice LDS: 8 float4 slots/row; value at (r,slot) is W[r][4*(slot ^ ((r>>3)&7))..].
// gl_lds dest linear + pre-swizzled global source (rule 21); read slot = q ^ (tx&7).
// zs: UNSWIZZLED [row][16 slots] — zf reads are wave-broadcast (bank-safe by nature),
// so linear layout lets every zf read fold to base+immediate (0 VALU). z ds_writes
// are bank-narrow but only ~1.5% of LDS ops — accepted.

// async global->LDS, 16B/lane; LDS dest = wave-uniform base + lane*16 (linear).
__device__ __forceinline__ void gl_lds16(const float* g, void* l) {
    __builtin_amdgcn_global_load_lds((const __attribute__((address_space(1))) void*)g,
                                     (__attribute__((address_space(3))) void*)l, 16, 0, 0);
}

// Fused: rowsq + argmin-GEMM (W double-buffered; barriers never drain fresh loads)
// + gather/ST/SSE/counts.
// Block: 64 rows x 1024 codes (4 chunks of 256). 256 thr = 8(ty) x 32(tx), 8x8 tile.
// dist mirrors np:  s1 = fl(rowsq + wsq);  v = fmaf(-2, dot, s1).
// Per-(row,code) dot: single sequential fmaf chain over d=0..255 in order
// (steps asc, q asc, x/y/z/w) — bitwise-matches BLAS k-order; validated absmax==0.0.
// DO NOT reorder. DO NOT add #pragma unroll to the q-loop (R4 spill lesson).
__global__ __launch_bounds__(256, 2) void vq_fused_kernel(
    const float* __restrict__ z, const float* __restrict__ W,
    const float* __restrict__ wsq, float* __restrict__ out,
    int* __restrict__ counts, float* __restrict__ sse)
{
    __shared__ float4 zs[BROWS * 16];   // 16 KB single buffer, linear (scratch at end)
    __shared__ float4 ws[2][CCH * 8];   // 2 x 32 KB double buffer
    const int tid = threadIdx.x;
    const int tx = tid & 31, ty = tid >> 5;
    const int w = tid >> 6, lane = tid & 63;
    const int txc = tx & 7;             // W read-swizzle constant
    const int row0 = blockIdx.x * BROWS;
    const int b = row0 >> 10, t0 = row0 & 1023;
    const size_t bbase = (size_t)b * DD * TT;
    const float* zbase = z + bbase + t0;

    // staging identities
    const int zr  = lane;            // z row 0..63 (coalesced over t)
    const int zq0 = w * 4;           // z q-groups: 4 per thread (of 16)
    const int wlr = lane >> 3;       // W lane row-in-8
    const int wls = lane & 7;        // W lane slot
    float4 zreg[4];

    // ---- prologue staging: W slice for step 0, z slab 0 (latency hides under rowsq)
    {
        char* dst = (char*)&ws[0][0] + (size_t)w * 8192;
        #pragma unroll
        for (int k = 0; k < 8; ++k) {
            const int r = w * 64 + k * 8 + wlr;
            gl_lds16(W + (size_t)r * DD + 4 * (wls ^ k), dst + k * 1024);
        }
        #pragma unroll
        for (int j = 0; j < 4; ++j) {
            const float* zp = zbase + (size_t)((zq0 + j) * 4) * TT + zr;
            zreg[j].x = zp[0]; zreg[j].y = zp[(size_t)TT];
            zreg[j].z = zp[(size_t)2 * TT]; zreg[j].w = zp[(size_t)3 * TT];
        }
    }

    // ---- rowsq (fp64, bitwise == ((g0+g1)+(g2+g3)) of 64-elem sequential chains)
    float rsq[8];
    {
        const int ro = lane & 15;          // row offset within wave's 16 rows
        const int g  = lane >> 4;          // d-quarter 0..3
        const float* zp = zbase + (size_t)g * 64 * TT + (16 * w + ro);
        double s = 0.0;
        #pragma unroll 4
        for (int d = 0; d < 64; ++d) { float v = zp[(size_t)d * TT]; s += (double)v * v; }
        s += __shfl_xor(s, 16);            // fp64 add commutative: bitwise safe
        s += __shfl_xor(s, 32);
        float f = (float)s;
        #pragma unroll
        for (int i = 0; i < 8; ++i) rsq[i] = __shfl(f, (ty & 1) * 8 + i);
    }

    float minv[8]; int mini[8];
    #pragma unroll
    for (int i = 0; i < 8; ++i) { minv[i] = 3.4e38f; mini[i] = 0; }

    float acc[8][8];
    float wq[8];

    for (int s = 0; s < NSTEP; ++s) {
        const int h = s & 1, sl = s & 7, ch = s >> 3;
        __syncthreads();   // sync_A: prev compute done; ws[s&1] gl_lds landed (issued
                           // a full compute phase ago -> drain ~free)
        if (h == 0) {
            // write z slab (steps s, s+1) from regs; linear layout
            #pragma unroll
            for (int j = 0; j < 4; ++j) zs[zr * 16 + zq0 + j] = zreg[j];
            __syncthreads();   // sync_B: only local ds_writes outstanding -> cheap
        }
        // issue next step's W staging NOW; lands during compute below
        if (s + 1 < NSTEP) {
            const int t = s + 1, sln = t & 7, chn = t >> 3;
            const float* wch = W + (size_t)(chn * CCH) * DD + sln * WSL;
            char* dst = (char*)&ws[t & 1][0] + (size_t)w * 8192;
            #pragma unroll
            for (int k = 0; k < 8; ++k) {
                const int r = w * 64 + k * 8 + wlr;
                gl_lds16(wch + (size_t)r * DD + 4 * (wls ^ k), dst + k * 1024);
            }
        }
        // prefetch z slab for steps s+2, s+3 (even steps only)
        if (h == 0 && s + 2 < NSTEP) {
            const int mn = ((s + 2) & 7) >> 1;
            #pragma unroll
            for (int j = 0; j < 4; ++j) {
                const float* zp = zbase + (size_t)(mn * 64 + (zq0 + j) * 4) * TT + zr;
                zreg[j].x = zp[0]; zreg[j].y = zp[(size_t)TT];
                zreg[j].z = zp[(size_t)2 * TT]; zreg[j].w = zp[(size_t)3 * TT];
            }
        }
        if (sl == 0) {
            #pragma unroll
            for (int i = 0; i < 8; ++i)
                #pragma unroll
                for (int j = 0; j < 8; ++j) acc[i][j] = 0.0f;
            #pragma unroll
            for (int j = 0; j < 8; ++j) wq[j] = wsq[ch * CCH + tx * 8 + j];
        }
        // 8x8x(32d) register-tile FMA; d-order: q ascending, then x,y,z,w
        // zf: one base reg + compile-time offsets (i*256B + q*16B) — 0 VALU/read.
        // wf: per-q base (xor+shl+add), then j*128B immediates.
        const int qb = 8 * h;
        const float4* wsb = &ws[h][0];
        const float4* zsb = &zs[ty * 128];
        __builtin_amdgcn_s_setprio(1);
        for (int q = 0; q < 8; ++q) {       // no unroll pragma (R4 spill lesson)
            const float4* wb = wsb + tx * 64 + (q ^ txc);
            const float4* zb = zsb + qb + q;
            float4 zf[8], wf[8];
            #pragma unroll
            for (int i = 0; i < 8; ++i) zf[i] = zb[i * 16];
            #pragma unroll
            for (int j = 0; j < 8; ++j) wf[j] = wb[j * 8];
            #pragma unroll
            for (int i = 0; i < 8; ++i)
                #pragma unroll
                for (int j = 0; j < 8; ++j) {
                    acc[i][j] = fmaf(zf[i].x, wf[j].x, acc[i][j]);
                    acc[i][j] = fmaf(zf[i].y, wf[j].y, acc[i][j]);
                    acc[i][j] = fmaf(zf[i].z, wf[j].z, acc[i][j]);
                    acc[i][j] = fmaf(zf[i].w, wf[j].w, acc[i][j]);
                }
        }
        __builtin_amdgcn_s_setprio(0);
        if (sl == 7) {
            // score + running argmin (codes ascending -> first-min like np.argmin)
            #pragma unroll
            for (int j = 0; j < 8; ++j) {
                int c = ch * CCH + tx * 8 + j;
                #pragma unroll
                for (int i = 0; i < 8; ++i) {
                    float s1 = rsq[i] + wq[j];               // rounding 1 (np A+B)
                    float v = fmaf(-2.0f, acc[i][j], s1);    // rounding 2 (np (A+B)-2P)
                    if (v < minv[i]) { minv[i] = v; mini[i] = c; }
                }
            }
        }
    }

    __syncthreads();                 // all compute done; zs becomes scratch
    int* idxs = (int*)&zs[0];        // 64 ints
    float* ssescr = (float*)&zs[0] + 64;
    // reduce across the 32 tx lanes of each row; ties -> lowest index
    #pragma unroll
    for (int i = 0; i < 8; ++i) {
        float v = minv[i]; int ix = mini[i];
        #pragma unroll
        for (int m = 1; m < 32; m <<= 1) {
            float ov = __shfl_xor(v, m);
            int   oi = __shfl_xor(ix, m);
            if (ov < v || (ov == v && oi < ix)) { v = ov; ix = oi; }
        }
        if (tx == 0) {
            idxs[ty * 8 + i] = ix;
            atomicAdd(&counts[ix], 1);
        }
    }
    __syncthreads();

    // ---- fused gather / straight-through / SSE over this block's 64 rows x 256 d
    const int tg = tid & 15;       // t-quarter (4 rows)
    const int dg = tid >> 4;       // 16 d-groups of 16
    const int t4 = tg * 4;
    int ixs[4];
    #pragma unroll
    for (int m = 0; m < 4; ++m) ixs[m] = idxs[t4 + m];
    float ssel = 0.0f;
    #pragma unroll
    for (int k4 = 0; k4 < 4; ++k4) {
        const int d0 = dg * 16 + k4 * 4;
        float wr[4][4];
        #pragma unroll
        for (int m = 0; m < 4; ++m) {
            float4 wv = *(const float4*)(W + (size_t)ixs[m] * DD + d0);
            wr[m][0] = wv.x; wr[m][1] = wv.y; wr[m][2] = wv.z; wr[m][3] = wv.w;
        }
        #pragma unroll
        for (int dd = 0; dd < 4; ++dd) {
            const int d = d0 + dd;
            const size_t base = bbase + (size_t)d * TT + t0 + t4;
            float4 zv = *(const float4*)(z + base);
            float e0 = wr[0][dd] - zv.x, e1 = wr[1][dd] - zv.y;
            float e2 = wr[2][dd] - zv.z, e3 = wr[3][dd] - zv.w;
            float4 o;
            o.x = zv.x + e0; o.y = zv.y + e1; o.z = zv.z + e2; o.w = zv.w + e3;
            *(float4*)(out + base) = o;
            ssel += (e0 * e0 + e1 * e1) + (e2 * e2 + e3 * e3);
        }
    }
    #pragma unroll
    for (int m = 32; m > 0; m >>= 1) ssel += __shfl_down(ssel, m);
    if (lane == 0) ssescr[w] = ssel;
    __syncthreads();
    if (tid == 0) atomicAdd(sse, (ssescr[0] + ssescr[1]) + (ssescr[2] + ssescr[3]));
}

// reg_loss = 1.25 * sse / numel ; perplexity = exp(-sum p*log(p+1e-10))
__global__ void finalize_kernel(const int* __restrict__ counts, const float* __restrict__ sse,
                                float* __restrict__ out) {
    float s = 0.0f;
    for (int k = threadIdx.x; k < KK; k += 256) {
        float p = (float)counts[k] / (float)NN;
        s += p * logf(p + 1e-10f);
    }
    #pragma unroll
    for (int m = 32; m > 0; m >>= 1) s += __shfl_down(s, m);
    __shared__ float wsum[4];
    if ((threadIdx.x & 63) == 0) wsum[threadIdx.x >> 6] = s;
    __syncthreads();
    if (threadIdx.x == 0) {
        float ent = (wsum[0] + wsum[1]) + (wsum[2] + wsum[3]);
        out[(size_t)BB * DD * TT]     = 1.25f * (*sse) / (float)(BB * DD * TT);
        out[(size_t)BB * DD * TT + 1] = expf(-ent);
    }
}

extern "C" void kernel_launch(void* const* d_in, const int* in_sizes, int n_in,
                              void* d_out, int out_size, void* d_ws, size_t ws_size,
                              hipStream_t stream) {
    const float* z = (const float*)d_in[0];   // (32, 256, 1024) fp32
    const float* W = (const float*)d_in[1];   // (1024, 256) fp32
    float* out = (float*)d_out;               // 8388608 + 2 fp32

    float* wsq    = (float*)d_ws;
    int*   counts = (int*)(wsq + 1024);
    float* sse    = (float*)(counts + 1024);

    prep_kernel<<<1024, 64, 0, stream>>>(W, wsq, counts, sse);
    vq_fused_kernel<<<NN / BROWS, 256, 0, stream>>>(z, W, wsq, out, counts, sse);
    finalize_kernel<<<1, 256, 0, stream>>>(counts, sse, out);
}